// Round 1
// baseline (104.472 us; speedup 1.0000x reference)
//
#include <hip/hip_runtime.h>
#include <hip/hip_bf16.h>

#define BATCH 8192
#define DIM   512
#define NCL   1024
#define ROWS  32
#define BK    32
#define NCH   (DIM / BK)   // 16 chunks
#define WPAD  40           // bf16 elems per cluster-chunk row (32 used + 8 pad) = 80 B: 16B-aligned frags, 2-way banks (free)
#define XPAD  520          // bf16 elems per x row (512 + 8): 1040 B stride, 16B-aligned, 2-way banks (free)

typedef __bf16 bf16x8 __attribute__((ext_vector_type(8)));
typedef float  f32x4  __attribute__((ext_vector_type(4)));

typedef const __attribute__((address_space(1))) void* gas_ptr;
typedef __attribute__((address_space(3))) void* las_ptr;

__device__ __forceinline__ unsigned short f2bf(float f) {
  union { float f; unsigned u; } v; v.f = f;
  unsigned r = v.u + 0x7fffu + ((v.u >> 16) & 1u);   // RNE, inputs finite
  return (unsigned short)(r >> 16);
}
__device__ __forceinline__ unsigned pk(float a, float b) {
  return (unsigned)f2bf(a) | ((unsigned)f2bf(b) << 16);
}

// Convert weight [1024][512] fp32 -> chunk-major padded bf16 [16][1024][WPAD], plus wsq[1024].
// One wave per cluster row; grid 256 x 256 threads.
__global__ __launch_bounds__(256) void prep_w(const float* __restrict__ w,
                                              __hip_bfloat16* __restrict__ wck,
                                              float* __restrict__ wsq) {
  int k    = blockIdx.x * 4 + (threadIdx.x >> 6);
  int lane = threadIdx.x & 63;
  const float4* wrow = (const float4*)(w + (size_t)k * DIM);
  float4 a = wrow[lane * 2 + 0];
  float4 b = wrow[lane * 2 + 1];
  float s = a.x*a.x + a.y*a.y + a.z*a.z + a.w*a.w
          + b.x*b.x + b.y*b.y + b.z*b.z + b.w*b.w;
  #pragma unroll
  for (int m = 32; m >= 1; m >>= 1) s += __shfl_xor(s, m, 64);
  if (lane == 0) wsq[k] = s;
  int c = lane >> 2;          // d-chunk of this lane's 8 elems (d0 = lane*8)
  int j = (lane & 3) * 8;     // offset within chunk
  uint4 p = { pk(a.x, a.y), pk(a.z, a.w), pk(b.x, b.y), pk(b.z, b.w) };
  *(uint4*)(wck + (size_t)(c * NCL + k) * WPAD + j) = p;   // 16B aligned: WPAD*2=80, j*2 in {0,16,32,48}
}

// Fused: 32 rows x 1024 cols per block, 8 waves (each wave: 128-col strip, 2x8 tiles of 16x16).
__global__ __launch_bounds__(512) void fused(const float* __restrict__ x,
                                             const __hip_bfloat16* __restrict__ wck,
                                             const float* __restrict__ wsq,
                                             float* __restrict__ out) {
  __shared__ __hip_bfloat16 xs[ROWS * XPAD];   // 33280 B
  __shared__ __hip_bfloat16 wt[NCL * WPAD];    // 81920 B
  __shared__ float wsq_s[NCL];                 // 4096 B
  __shared__ float xsq_s[ROWS];
  __shared__ float red[ROWS][9];               // 8 waves + pad
  __shared__ float rowtot[ROWS];

  const int tid = threadIdx.x;
  const int r0  = blockIdx.x * ROWS;

  // ---- stage x fp32->bf16 + per-row sum of squares (fp32 exact) ----
  {
    int row = tid >> 4;          // 0..31
    int seg = tid & 15;          // 32 elems each
    const float4* src = (const float4*)(x + (size_t)(r0 + row) * DIM + seg * 32);
    float ss = 0.f;
    #pragma unroll
    for (int i = 0; i < 8; ++i) {
      float4 v = src[i];
      ss += v.x*v.x + v.y*v.y + v.z*v.z + v.w*v.w;
      uint2 p = { pk(v.x, v.y), pk(v.z, v.w) };
      *(uint2*)(xs + row * XPAD + seg * 32 + i * 4) = p;
    }
    ss += __shfl_xor(ss, 1, 64);
    ss += __shfl_xor(ss, 2, 64);
    ss += __shfl_xor(ss, 4, 64);
    ss += __shfl_xor(ss, 8, 64);
    if (seg == 0) xsq_s[row] = ss;
    wsq_s[tid]       = wsq[tid];
    wsq_s[tid + 512] = wsq[tid + 512];
  }

  const int wave = tid >> 6;
  const int lane = tid & 63;
  const int m16  = lane & 15;
  const int quad = lane >> 4;
  const int col0 = wave * 128;

  f32x4 acc[2][8];
  #pragma unroll
  for (int rt = 0; rt < 2; ++rt)
    #pragma unroll
    for (int ct = 0; ct < 8; ++ct)
      acc[rt][ct] = (f32x4){0.f, 0.f, 0.f, 0.f};

  for (int c = 0; c < NCH; ++c) {
    // async stage weight chunk c (81920 B = 10 x 512 lanes x 16 B), verbatim layout
    {
      const char* g = (const char*)wck + (size_t)c * (NCL * WPAD * 2);
      #pragma unroll
      for (int it = 0; it < 10; ++it) {
        int off = (it * 512 + tid) * 16;
        __builtin_amdgcn_global_load_lds((gas_ptr)(g + off), (las_ptr)((char*)wt + off), 16, 0, 0);
      }
    }
    __syncthreads();   // drains vmcnt (staging) + covers xs/wsq_s writes on first iter

    bf16x8 a0 = *(const bf16x8*)(xs + ( 0 + m16) * XPAD + c * BK + quad * 8);
    bf16x8 a1 = *(const bf16x8*)(xs + (16 + m16) * XPAD + c * BK + quad * 8);
    #pragma unroll
    for (int ct = 0; ct < 8; ++ct) {
      bf16x8 bf = *(const bf16x8*)(wt + (col0 + ct * 16 + m16) * WPAD + quad * 8);
      acc[0][ct] = __builtin_amdgcn_mfma_f32_16x16x32_bf16(a0, bf, acc[0][ct], 0, 0, 0);
      acc[1][ct] = __builtin_amdgcn_mfma_f32_16x16x32_bf16(a1, bf, acc[1][ct], 0, 0, 0);
    }
    __syncthreads();   // all waves done reading wt before next chunk overwrites
  }

  // ---- epilogue: dist -> q_unnorm, row sums, normalize ----
  // C/D layout: col = lane&15 (cluster), row = quad*4 + reg (verified m89/m91)
  float part[2][4];
  #pragma unroll
  for (int rt = 0; rt < 2; ++rt)
    #pragma unroll
    for (int i = 0; i < 4; ++i) part[rt][i] = 0.f;

  #pragma unroll
  for (int rt = 0; rt < 2; ++rt) {
    float xq[4];
    #pragma unroll
    for (int i = 0; i < 4; ++i) xq[i] = xsq_s[rt * 16 + quad * 4 + i];
    #pragma unroll
    for (int ct = 0; ct < 8; ++ct) {
      float wq = wsq_s[col0 + ct * 16 + m16];
      #pragma unroll
      for (int i = 0; i < 4; ++i) {
        float dist = fmaxf(xq[i] + wq - 2.f * acc[rt][ct][i], 0.f);
        float qu = 1.f / (1.f + dist);    // ALPHA=1: (1+dist)^-1 exactly
        acc[rt][ct][i] = qu;
        part[rt][i] += qu;
      }
    }
  }
  // reduce across the 16 lanes sharing each row (same quad, m16 = 0..15)
  #pragma unroll
  for (int rt = 0; rt < 2; ++rt)
    #pragma unroll
    for (int i = 0; i < 4; ++i) {
      float s = part[rt][i];
      s += __shfl_xor(s, 1, 64);
      s += __shfl_xor(s, 2, 64);
      s += __shfl_xor(s, 4, 64);
      s += __shfl_xor(s, 8, 64);
      part[rt][i] = s;
    }
  if (m16 == 0) {
    #pragma unroll
    for (int rt = 0; rt < 2; ++rt)
      #pragma unroll
      for (int i = 0; i < 4; ++i)
        red[rt * 16 + quad * 4 + i][wave] = part[rt][i];
  }
  __syncthreads();
  if (tid < ROWS) {
    float t = 0.f;
    #pragma unroll
    for (int w2 = 0; w2 < 8; ++w2) t += red[tid][w2];
    rowtot[tid] = 1.f / t;
  }
  __syncthreads();
  #pragma unroll
  for (int rt = 0; rt < 2; ++rt) {
    #pragma unroll
    for (int i = 0; i < 4; ++i) {
      int r = rt * 16 + quad * 4 + i;
      float inv = rowtot[r];
      float* orow = out + (size_t)(r0 + r) * NCL + col0 + m16;
      #pragma unroll
      for (int ct = 0; ct < 8; ++ct)
        orow[ct * 16] = acc[rt][ct][i] * inv;   // 16-lane 64B coalesced segments
    }
  }
}

extern "C" void kernel_launch(void* const* d_in, const int* in_sizes, int n_in,
                              void* d_out, int out_size, void* d_ws, size_t ws_size,
                              hipStream_t stream) {
  const float* x = (const float*)d_in[0];   // [8192][512] fp32
  const float* w = (const float*)d_in[1];   // [1024][512] fp32
  __hip_bfloat16* wck = (__hip_bfloat16*)d_ws;                          // 16*1024*40*2 = 1,310,720 B
  float* wsq = (float*)((char*)d_ws + (size_t)NCH * NCL * WPAD * 2);    // + 4 KB
  float* out = (float*)d_out;

  hipLaunchKernelGGL(prep_w, dim3(NCL / 4), dim3(256), 0, stream, w, wck, wsq);
  hipLaunchKernelGGL(fused, dim3(BATCH / ROWS), dim3(512), 0, stream, x, wck, wsq, out);
}

// Round 2
// 104.144 us; speedup vs baseline: 1.0032x; 1.0032x over previous
//
#include <hip/hip_runtime.h>
#include <hip/hip_bf16.h>

#define BATCH 8192
#define DIM   512
#define NCL   1024
#define ROWS  32
#define BK    32
#define NCH   (DIM / BK)   // 16 chunks of 32 along D

typedef __bf16 bf16x8 __attribute__((ext_vector_type(8)));
typedef float  f32x4  __attribute__((ext_vector_type(4)));

__device__ __forceinline__ unsigned short f2bf(float f) {
  union { float f; unsigned u; } v; v.f = f;
  unsigned r = v.u + 0x7fffu + ((v.u >> 16) & 1u);   // RNE, inputs finite
  return (unsigned short)(r >> 16);
}
__device__ __forceinline__ unsigned pk(float a, float b) {
  return (unsigned)f2bf(a) | ((unsigned)f2bf(b) << 16);
}

// weight [1024][512] fp32 -> chunk-major bf16 wck[16][1024][32] (unpadded: B-frag
// reads from global are 64B-line exact), plus wsq[1024]. One wave per cluster row.
__global__ __launch_bounds__(256) void prep_w(const float* __restrict__ w,
                                              __hip_bfloat16* __restrict__ wck,
                                              float* __restrict__ wsq) {
  int k    = blockIdx.x * 4 + (threadIdx.x >> 6);
  int lane = threadIdx.x & 63;
  const float4* wrow = (const float4*)(w + (size_t)k * DIM);
  float4 a = wrow[lane * 2 + 0];
  float4 b = wrow[lane * 2 + 1];
  float s = a.x*a.x + a.y*a.y + a.z*a.z + a.w*a.w
          + b.x*b.x + b.y*b.y + b.z*b.z + b.w*b.w;
  #pragma unroll
  for (int m = 32; m >= 1; m >>= 1) s += __shfl_xor(s, m, 64);
  if (lane == 0) wsq[k] = s;
  int c = lane >> 2;          // this lane's 8 elems (d0 = lane*8) live in chunk c
  int j = (lane & 3) * 8;     // offset within chunk
  uint4 p = { pk(a.x, a.y), pk(a.z, a.w), pk(b.x, b.y), pk(b.z, b.w) };
  *(uint4*)(wck + ((size_t)c * NCL + k) * BK + j) = p;   // 16B aligned
}

// Fused: 32 rows x 1024 cols per block, 8 waves (each: 128-col strip, 2x8 16x16 tiles).
// A-fragments pre-swizzled in LDS (conflict-free ds_read_b128); B-fragments read
// DIRECTLY from L2-resident wck (1KB contiguous per instr) -> zero K-loop barriers.
__global__ __launch_bounds__(512) void fused(const float* __restrict__ x,
                                             const __hip_bfloat16* __restrict__ wck,
                                             const float* __restrict__ wsq,
                                             float* __restrict__ out) {
  // xs2[c][rt][lane*8 + j]: MFMA A-fragment layout, tile (c, rt) = 512 elems (1 KB)
  __shared__ __align__(16) __hip_bfloat16 xs2[NCH * 2 * 512];   // 32 KB
  __shared__ float wsq_s[NCL];                                  // 4 KB
  __shared__ float xsq_s[ROWS];
  __shared__ float red[ROWS][9];                                // 8 waves + pad
  __shared__ float rowtot[ROWS];

  const int tid = threadIdx.x;
  const int r0  = blockIdx.x * ROWS;

  // ---- stage x fp32->bf16 into A-frag layout + per-row sum of squares ----
  {
    int row = tid >> 4;          // 0..31
    int seg = tid & 15;          // = chunk c: this thread owns 32 consecutive d
    int rt  = row >> 4, m = row & 15;
    const float4* src = (const float4*)(x + (size_t)(r0 + row) * DIM + seg * BK);
    __hip_bfloat16* dst = xs2 + (seg * 2 + rt) * 512 + m * 8;
    float ss = 0.f;
    #pragma unroll
    for (int i = 0; i < 8; ++i) {       // quad = i>>1, half = i&1
      float4 v = src[i];
      ss += v.x*v.x + v.y*v.y + v.z*v.z + v.w*v.w;
      uint2 p = { pk(v.x, v.y), pk(v.z, v.w) };
      *(uint2*)(dst + (i >> 1) * 128 + (i & 1) * 4) = p;
    }
    ss += __shfl_xor(ss, 1, 64);
    ss += __shfl_xor(ss, 2, 64);
    ss += __shfl_xor(ss, 4, 64);
    ss += __shfl_xor(ss, 8, 64);
    if (seg == 0) xsq_s[row] = ss;
    wsq_s[tid]       = wsq[tid];
    wsq_s[tid + 512] = wsq[tid + 512];
  }

  const int wave = tid >> 6;
  const int lane = tid & 63;
  const int m16  = lane & 15;
  const int quad = lane >> 4;
  const int col0 = wave * 128;

  f32x4 acc[2][8];
  #pragma unroll
  for (int rt = 0; rt < 2; ++rt)
    #pragma unroll
    for (int ct = 0; ct < 8; ++ct)
      acc[rt][ct] = (f32x4){0.f, 0.f, 0.f, 0.f};

  __syncthreads();   // xs2 / wsq_s visible; the ONLY barrier before the epilogue

  #pragma unroll 2
  for (int c = 0; c < NCH; ++c) {
    bf16x8 a0 = *(const bf16x8*)(xs2 + (c * 2 + 0) * 512 + lane * 8);
    bf16x8 a1 = *(const bf16x8*)(xs2 + (c * 2 + 1) * 512 + lane * 8);
    const __hip_bfloat16* wp = wck + ((size_t)c * NCL + col0 + m16) * BK + quad * 8;
    #pragma unroll
    for (int ct = 0; ct < 8; ++ct) {
      bf16x8 bf = *(const bf16x8*)(wp + ct * (16 * BK));   // 1KB contiguous / instr (L2)
      acc[0][ct] = __builtin_amdgcn_mfma_f32_16x16x32_bf16(a0, bf, acc[0][ct], 0, 0, 0);
      acc[1][ct] = __builtin_amdgcn_mfma_f32_16x16x32_bf16(a1, bf, acc[1][ct], 0, 0, 0);
    }
  }

  // ---- epilogue: dist -> q_unnorm, row sums, normalize ----
  // C/D layout: col = lane&15, row = quad*4 + reg (verified m89/m91)
  float part[2][4];
  #pragma unroll
  for (int rt = 0; rt < 2; ++rt)
    #pragma unroll
    for (int i = 0; i < 4; ++i) part[rt][i] = 0.f;

  #pragma unroll
  for (int rt = 0; rt < 2; ++rt) {
    float xq[4];
    #pragma unroll
    for (int i = 0; i < 4; ++i) xq[i] = xsq_s[rt * 16 + quad * 4 + i];
    #pragma unroll
    for (int ct = 0; ct < 8; ++ct) {
      float wq = wsq_s[col0 + ct * 16 + m16];
      #pragma unroll
      for (int i = 0; i < 4; ++i) {
        float dist = fmaxf(xq[i] + wq - 2.f * acc[rt][ct][i], 0.f);
        float qu = 1.f / (1.f + dist);    // ALPHA=1: (1+dist)^-1 exact
        acc[rt][ct][i] = qu;
        part[rt][i] += qu;
      }
    }
  }
  #pragma unroll
  for (int rt = 0; rt < 2; ++rt)
    #pragma unroll
    for (int i = 0; i < 4; ++i) {
      float s = part[rt][i];
      s += __shfl_xor(s, 1, 64);
      s += __shfl_xor(s, 2, 64);
      s += __shfl_xor(s, 4, 64);
      s += __shfl_xor(s, 8, 64);
      part[rt][i] = s;
    }
  if (m16 == 0) {
    #pragma unroll
    for (int rt = 0; rt < 2; ++rt)
      #pragma unroll
      for (int i = 0; i < 4; ++i)
        red[rt * 16 + quad * 4 + i][wave] = part[rt][i];
  }
  __syncthreads();
  if (tid < ROWS) {
    float t = 0.f;
    #pragma unroll
    for (int w2 = 0; w2 < 8; ++w2) t += red[tid][w2];
    rowtot[tid] = 1.f / t;
  }
  __syncthreads();
  #pragma unroll
  for (int rt = 0; rt < 2; ++rt) {
    #pragma unroll
    for (int i = 0; i < 4; ++i) {
      int r = rt * 16 + quad * 4 + i;
      float inv = rowtot[r];
      float* orow = out + (size_t)(r0 + r) * NCL + col0 + m16;
      #pragma unroll
      for (int ct = 0; ct < 8; ++ct)
        orow[ct * 16] = acc[rt][ct][i] * inv;   // 16-lane 64B coalesced segments
    }
  }
}

extern "C" void kernel_launch(void* const* d_in, const int* in_sizes, int n_in,
                              void* d_out, int out_size, void* d_ws, size_t ws_size,
                              hipStream_t stream) {
  const float* x = (const float*)d_in[0];   // [8192][512] fp32
  const float* w = (const float*)d_in[1];   // [1024][512] fp32
  __hip_bfloat16* wck = (__hip_bfloat16*)d_ws;                      // 16*1024*32*2 = 1 MB
  float* wsq = (float*)((char*)d_ws + (size_t)NCH * NCL * BK * 2);  // +4 KB
  float* out = (float*)d_out;

  hipLaunchKernelGGL(prep_w, dim3(NCL / 4), dim3(256), 0, stream, w, wck, wsq);
  hipLaunchKernelGGL(fused, dim3(BATCH / ROWS), dim3(512), 0, stream, x, wck, wsq, out);
}